// Round 2
// baseline (156.752 us; speedup 1.0000x reference)
//
#include <hip/hip_runtime.h>
#include <hip/hip_bf16.h>
#include <math.h>

#define S_LEN 1024
#define BATCH 4
#define HID 1024
#define NHEADS 16
#define DHEAD 64
#define NTOT 64
#define M_ROWS 4096

typedef unsigned short u16;
typedef unsigned int u32;
typedef __bf16 bf16x8 __attribute__((ext_vector_type(8)));
typedef float f32x4 __attribute__((ext_vector_type(4)));

__device__ __forceinline__ u16 f2bf(float x) {
    __hip_bfloat16 h = __float2bfloat16(x);
    return *(u16*)&h;
}

__device__ __forceinline__ float fexp2(float x) {
#if __has_builtin(__builtin_amdgcn_exp2f)
    return __builtin_amdgcn_exp2f(x);
#else
    return __expf(x * 0.6931471805599453f);
#endif
}

// async global->LDS, 16B/lane; LDS dest = wave-uniform base + lane*16
__device__ __forceinline__ void gll16(const u16* g, u16* l) {
    __builtin_amdgcn_global_load_lds(
        (const __attribute__((address_space(1))) u32*)g,
        (__attribute__((address_space(3))) u32*)l, 16, 0, 0);
}

// ---------------------------------------------------------------------------
// fused fp32 -> bf16 convert for X and the three W matrices
// ---------------------------------------------------------------------------
__global__ __launch_bounds__(256) void cvt_all(
    const float* __restrict__ X, const float* __restrict__ wq,
    const float* __restrict__ wk, const float* __restrict__ wv,
    u16* __restrict__ Xb, u16* __restrict__ Wb)
{
    const int bid = blockIdx.x;
    const float* src;
    u16* dst;
    size_t off;
    if (bid < 4096) {            // X: 4M elems
        src = X; dst = Xb; off = (size_t)bid * 1024;
    } else {                     // W: 3 x 1M elems
        const int wb = bid - 4096;
        const int which = wb >> 10;
        src = (which == 0) ? wq : (which == 1) ? wk : wv;
        dst = Wb + (size_t)which * HID * HID;
        off = (size_t)(wb & 1023) * 1024;
    }
    const size_t idx = off + threadIdx.x * 4;
    float4 x = *(const float4*)(src + idx);
    *(ushort4*)(dst + idx) = make_ushort4(f2bf(x.x), f2bf(x.y), f2bf(x.z), f2bf(x.w));
}

// ---------------------------------------------------------------------------
// QKV projection: 128x128 tile, BK=64, XOR-swizzled LDS via pre-swizzled
// global_load_lds source.  Q,K -> [n][s][d] bf16;  V -> V^T [n][d][s] bf16.
// (unchanged this round)
// ---------------------------------------------------------------------------
__global__ __launch_bounds__(256, 3) void qkv_mfma(
    const u16* __restrict__ Xb, const u16* __restrict__ Wb,
    const float* __restrict__ bq, const float* __restrict__ bk,
    const float* __restrict__ bv,
    u16* __restrict__ Qb, u16* __restrict__ Kb, u16* __restrict__ VT)
{
    const int m0 = blockIdx.x * 128;
    const int n0 = blockIdx.y * 128;
    const int which = blockIdx.z;

    __shared__ __align__(16) u16 As[128 * 64];   // 16 KB
    __shared__ __align__(16) u16 Bs[128 * 64];   // 16 KB

    const int tid = threadIdx.x;
    const int lane = tid & 63;
    const int w = tid >> 6;
    const int wm = w & 1, wn = w >> 1;
    const int quad = lane >> 4;
    const int l15 = lane & 15;
    const int r7 = l15 & 7;

    const u16* W = Wb + (size_t)which * HID * HID;

    f32x4 acc[4][4];
    #pragma unroll
    for (int i = 0; i < 4; ++i)
        #pragma unroll
        for (int j = 0; j < 4; ++j)
            #pragma unroll
            for (int r = 0; r < 4; ++r) acc[i][j][r] = 0.0f;

    const int srow = lane >> 3;
    const int scg  = ((lane & 7) ^ srow) * 8;    // u16 units

    for (int k0 = 0; k0 < HID; k0 += 64) {
        #pragma unroll
        for (int c = 0; c < 4; ++c) {
            const int seg = w * 4 + c;
            const int row = seg * 8 + srow;
            gll16(Xb + (size_t)(m0 + row) * HID + k0 + scg, As + seg * 512);
            gll16(W  + (size_t)(n0 + row) * HID + k0 + scg, Bs + seg * 512);
        }
        __syncthreads();

        #pragma unroll
        for (int kk = 0; kk < 2; ++kk) {
            const int xo = ((kk * 4 + quad) ^ r7) * 8;   // swizzled 16B slot
            bf16x8 af[4], bf[4];
            #pragma unroll
            for (int i = 0; i < 4; ++i)
                af[i] = *(const bf16x8*)(As + (wm * 64 + i * 16 + l15) * 64 + xo);
            #pragma unroll
            for (int j = 0; j < 4; ++j)
                bf[j] = *(const bf16x8*)(Bs + (wn * 64 + j * 16 + l15) * 64 + xo);
            #pragma unroll
            for (int i = 0; i < 4; ++i)
                #pragma unroll
                for (int j = 0; j < 4; ++j)
                    acc[i][j] = __builtin_amdgcn_mfma_f32_16x16x32_bf16(
                        af[i], bf[j], acc[i][j], 0, 0, 0);
        }
        __syncthreads();
    }

    const float* bias = (which == 0) ? bq : (which == 1) ? bk : bv;
    #pragma unroll
    for (int j = 0; j < 4; ++j) {
        const int o = n0 + wn * 64 + j * 16 + l15;
        const float bias_v = bias[o];
        const int head = o >> 6, d = o & 63;
        #pragma unroll
        for (int i = 0; i < 4; ++i) {
            const int mbase = m0 + wm * 64 + i * 16 + quad * 4;
            const int s = mbase >> 2;
            #pragma unroll
            for (int r = 0; r < 4; ++r) {
                const int n = r * NHEADS + head;
                const u16 hv = f2bf(acc[i][j][r] + bias_v);
                if (which == 0)
                    Qb[((size_t)n * S_LEN + s) * DHEAD + d] = hv;
                else if (which == 1)
                    Kb[((size_t)n * S_LEN + s) * DHEAD + d] = hv;
                else
                    VT[(size_t)n * (DHEAD * S_LEN) + (size_t)d * S_LEN + s] = hv;
            }
        }
    }
}

// ---------------------------------------------------------------------------
// Flash attention, transposed-score formulation.  QBLK=64 this round:
// 1024 blocks (16 s-blocks x 64 heads), 4 waves x 16 q, 3 blocks/CU
// (__launch_bounds__(256,3), 45 KB LDS) -> 3 waves/SIMD for latency hiding.
// Per 64-key tile:
//   P^T = K·Q^T  (swapped MFMA operands) -> lane l15 = q, rows = t
//   pack f32x4 -> ushort4 into Ps[q][t], same-wave consume (no barrier)
//   O^T += V^T·P^T
// Mask row pre-transformed to exp2 domain in LDS (prologue) -> no per-tile
// HBM load on the critical path; per-quad reads broadcast.
// XCD-chunked swizzle: 128 consecutive blocks (= 8 whole heads) per XCD.
// ---------------------------------------------------------------------------
__global__ __launch_bounds__(256, 3) void attn_mfma(
    const u16* __restrict__ Qb, const u16* __restrict__ Kb,
    const u16* __restrict__ VT, const float* __restrict__ mask,
    float* __restrict__ out)
{
    const int bid = blockIdx.x;
    const int swz = (bid & 7) * 128 + (bid >> 3);   // bijective, 1024%8==0
    const int n = swz >> 4;           // head index 0..63
    const int s0 = (swz & 15) * 64;   // q-block
    const int b = n >> 4, head = n & 15;

    __shared__ __align__(16) char smem[46080];
    u16* Kbuf = (u16*)smem;             // [2][4096] u16 = 16 KB
    u16* Vbuf = (u16*)(smem + 16384);   // [2][4096] u16 = 16 KB
    u16* Ps   = (u16*)(smem + 32768);   // [64][72] u16 = 9216 B
    float* Ms = (float*)(smem + 41984); // [1024] f32 = 4 KB (exp2-domain mask)
    float* Of = (float*)smem;           // [64][72] f32 overlay, epilogue

    const int tid = threadIdx.x;
    const int lane = tid & 63;
    const int w = tid >> 6;
    const int quad = lane >> 4;
    const int l15 = lane & 15;
    const size_t nbase = (size_t)n * S_LEN * DHEAD;

    const float LOG2E = 1.44269504f;
    const float SCL2  = 0.18033688f;    // 0.125 * log2(e)
    const float MOFF  = -23.0831099f;   // -16 * log2(e)

    // XOR'd chunk offsets for swizzled K/V frag reads (row&7 == l15&7)
    const int xs0 = ((quad ^ (l15 & 7)) * 8);
    const int xs1 = (((4 + quad) ^ (l15 & 7)) * 8);

    // staging lane mapping (XOR-permuted global chunk -> swizzled LDS tile)
    const int srow = lane >> 3;
    const int scg  = (lane & 7) ^ (srow & 7);

    // mask row -> LDS, pre-transformed (before first barrier)
    {
        float4 mv = *(const float4*)(mask + (size_t)n * S_LEN + tid * 4);
        Ms[tid * 4 + 0] = fmaf(mv.x, LOG2E, MOFF);
        Ms[tid * 4 + 1] = fmaf(mv.y, LOG2E, MOFF);
        Ms[tid * 4 + 2] = fmaf(mv.z, LOG2E, MOFF);
        Ms[tid * 4 + 3] = fmaf(mv.w, LOG2E, MOFF);
    }

    // Q fragments in registers (MFMA B-operand: Q^T); this wave owns 16 q
    const int q = w * 16 + l15;
    bf16x8 qf[2];
    #pragma unroll
    for (int st = 0; st < 2; ++st)
        qf[st] = *(const bf16x8*)(Qb + nbase +
            (size_t)(s0 + q) * 64 + st * 32 + quad * 8);

    f32x4 O[4];             // O^T[d][q] accumulators
    float l_lane = 0.0f;    // per-lane l partial (q fixed per lane)
    #pragma unroll
    for (int jt = 0; jt < 4; ++jt)
        #pragma unroll
        for (int r = 0; r < 4; ++r) O[jt][r] = 0.0f;

    // prefetch tile 0 (8 segs of 1 KB each for K and V)
    {
        #pragma unroll
        for (int c = 0; c < 2; ++c) {
            const int seg = w * 2 + c;
            const int row = seg * 8 + srow;
            gll16(Kb + nbase + (size_t)row * 64 + scg * 8, Kbuf + seg * 512);
            gll16(VT + nbase + (size_t)row * S_LEN + scg * 8, Vbuf + seg * 512);
        }
    }
    __syncthreads();

    for (int it = 0; it < 16; ++it) {
        const int t0 = it * 64;
        const u16* kb = Kbuf + (it & 1) * 4096;
        const u16* vb = Vbuf + (it & 1) * 4096;

        if (it < 15) {
            u16* kd = Kbuf + ((it + 1) & 1) * 4096;
            u16* vd = Vbuf + ((it + 1) & 1) * 4096;
            #pragma unroll
            for (int c = 0; c < 2; ++c) {
                const int seg = w * 2 + c;
                const int row = seg * 8 + srow;
                gll16(Kb + nbase + (size_t)(t0 + 64 + row) * 64 + scg * 8, kd + seg * 512);
                gll16(VT + nbase + (size_t)row * S_LEN + t0 + 64 + scg * 8, vd + seg * 512);
            }
        }

        // ---- P^T = K·Q^T : sc[j] rows t'=quad*4+r (t = t0+j*16+t'), col q=l15
        f32x4 sc[4];
        #pragma unroll
        for (int j = 0; j < 4; ++j)
            #pragma unroll
            for (int r = 0; r < 4; ++r) sc[j][r] = 0.0f;

        __builtin_amdgcn_s_setprio(1);
        #pragma unroll
        for (int st = 0; st < 2; ++st) {
            const int xo = st ? xs1 : xs0;
            bf16x8 kf[4];
            #pragma unroll
            for (int j = 0; j < 4; ++j)
                kf[j] = *(const bf16x8*)(kb + (j * 16 + l15) * 64 + xo);
            #pragma unroll
            for (int j = 0; j < 4; ++j)
                sc[j] = __builtin_amdgcn_mfma_f32_16x16x32_bf16(
                    kf[j], qf[st], sc[j], 0, 0, 0);
        }
        __builtin_amdgcn_s_setprio(0);

        // ---- softmax (fixed max, exp2 form; mask from LDS, broadcast) ----
        #pragma unroll
        for (int j = 0; j < 4; ++j) {
            float4 mb = *(const float4*)(Ms + t0 + j * 16 + quad * 4);
            const float p0 = fexp2(fmaf(sc[j][0], SCL2, mb.x));
            const float p1 = fexp2(fmaf(sc[j][1], SCL2, mb.y));
            const float p2 = fexp2(fmaf(sc[j][2], SCL2, mb.z));
            const float p3 = fexp2(fmaf(sc[j][3], SCL2, mb.w));
            l_lane += (p0 + p1) + (p2 + p3);
            *(ushort4*)(Ps + q * 72 + j * 16 + quad * 4) =
                make_ushort4(f2bf(p0), f2bf(p1), f2bf(p2), f2bf(p3));
        }
        // same-wave produce/consume of Ps rows -> no barrier

        // ---- O^T += V^T·P^T ----
        __builtin_amdgcn_s_setprio(1);
        #pragma unroll
        for (int st = 0; st < 2; ++st) {
            const int xo = st ? xs1 : xs0;
            bf16x8 vf[4];
            #pragma unroll
            for (int jt = 0; jt < 4; ++jt)
                vf[jt] = *(const bf16x8*)(vb + (jt * 16 + l15) * 64 + xo);
            bf16x8 pf = *(const bf16x8*)(Ps + q * 72 + st * 32 + quad * 8);
            #pragma unroll
            for (int jt = 0; jt < 4; ++jt)
                O[jt] = __builtin_amdgcn_mfma_f32_16x16x32_bf16(
                    vf[jt], pf, O[jt], 0, 0, 0);
        }
        __builtin_amdgcn_s_setprio(0);

        __syncthreads();   // buffer reads done; next prefetch may overwrite
    }

    // ---- epilogue ----
    float l = l_lane;
    l += __shfl_xor(l, 16);
    l += __shfl_xor(l, 32);
    const float inv_l = 1.0f / l;
    __syncthreads();   // all waves done with Kbuf/Vbuf before overlay

    #pragma unroll
    for (int jt = 0; jt < 4; ++jt)
        #pragma unroll
        for (int r = 0; r < 4; ++r)
            Of[q * 72 + jt * 16 + quad * 4 + r] = O[jt][r] * inv_l;
    __syncthreads();

    const int tx = tid & 15, ty = tid >> 4;
    #pragma unroll
    for (int p = 0; p < 4; ++p) {
        const int qq = p * 16 + ty;
        float4 v = *(const float4*)(Of + qq * 72 + tx * 4);
        *(float4*)(out + (size_t)(s0 + qq) * (BATCH * HID) + (size_t)b * HID +
                   head * DHEAD + tx * 4) = v;
    }
}

extern "C" void kernel_launch(void* const* d_in, const int* in_sizes, int n_in,
                              void* d_out, int out_size, void* d_ws, size_t ws_size,
                              hipStream_t stream)
{
    const float* X    = (const float*)d_in[0];
    const float* mask = (const float*)d_in[1];
    const float* Wq   = (const float*)d_in[2];
    const float* bq   = (const float*)d_in[3];
    const float* Wk   = (const float*)d_in[4];
    const float* bk   = (const float*)d_in[5];
    const float* Wv   = (const float*)d_in[6];
    const float* bv   = (const float*)d_in[7];
    float* out = (float*)d_out;

    const size_t MX = (size_t)M_ROWS * HID;   // 4M elems
    const size_t MW = (size_t)HID * HID;      // 1M elems
    u16* wsp = (u16*)d_ws;
    u16* Xb = wsp;
    u16* Wb = Xb + MX;          // 3 matrices
    u16* Qb = Wb + 3 * MW;
    u16* Kb = Qb + MX;
    u16* VT = Kb + MX;          // total 19M u16 = 38 MB

    cvt_all<<<dim3(4096 + 3072), 256, 0, stream>>>(X, Wq, Wk, Wv, Xb, Wb);
    qkv_mfma<<<dim3(M_ROWS / 128, HID / 128, 3), 256, 0, stream>>>(
        Xb, Wb, bq, bk, bv, Qb, Kb, VT);
    attn_mfma<<<dim3(S_LEN / 64 * NTOT), 256, 0, stream>>>(Qb, Kb, VT, mask, out);
}

// Round 3
// 146.508 us; speedup vs baseline: 1.0699x; 1.0699x over previous
//
#include <hip/hip_runtime.h>
#include <hip/hip_bf16.h>
#include <math.h>

#define S_LEN 1024
#define BATCH 4
#define HID 1024
#define NHEADS 16
#define DHEAD 64
#define NTOT 64
#define M_ROWS 4096

typedef unsigned short u16;
typedef unsigned int u32;
typedef __bf16 bf16x8 __attribute__((ext_vector_type(8)));
typedef float f32x4 __attribute__((ext_vector_type(4)));

__device__ __forceinline__ u16 f2bf(float x) {
    __hip_bfloat16 h = __float2bfloat16(x);
    return *(u16*)&h;
}

__device__ __forceinline__ float fexp2(float x) {
#if __has_builtin(__builtin_amdgcn_exp2f)
    return __builtin_amdgcn_exp2f(x);
#else
    return __expf(x * 0.6931471805599453f);
#endif
}

// pack two f32 -> one u32 of 2x bf16 (RNE), gfx950 v_cvt_pk_bf16_f32
__device__ __forceinline__ u32 cvtpk(float a, float b) {
    u32 r;
    asm("v_cvt_pk_bf16_f32 %0, %1, %2" : "=v"(r) : "v"(a), "v"(b));
    return r;
}

// swap lanes 16-31 of a with lanes 0-15 of b (and 48-63 with 32-47):
// a' = [a.q0|b.q0|a.q2|b.q2], b' = [a.q1|b.q1|a.q3|b.q3]  (q = 16-lane row)
__device__ __forceinline__ void pl16swap(u32& a, u32& b) {
    asm("v_permlane16_swap_b32 %0, %1" : "+v"(a), "+v"(b));
}

// async global->LDS, 16B/lane; LDS dest = wave-uniform base + lane*16
__device__ __forceinline__ void gll16(const u16* g, u16* l) {
    __builtin_amdgcn_global_load_lds(
        (const __attribute__((address_space(1))) u32*)g,
        (__attribute__((address_space(3))) u32*)l, 16, 0, 0);
}

// ---------------------------------------------------------------------------
// fused fp32 -> bf16 convert for X and the three W matrices
// ---------------------------------------------------------------------------
__global__ __launch_bounds__(256) void cvt_all(
    const float* __restrict__ X, const float* __restrict__ wq,
    const float* __restrict__ wk, const float* __restrict__ wv,
    u16* __restrict__ Xb, u16* __restrict__ Wb)
{
    const int bid = blockIdx.x;
    const float* src;
    u16* dst;
    size_t off;
    if (bid < 4096) {            // X: 4M elems
        src = X; dst = Xb; off = (size_t)bid * 1024;
    } else {                     // W: 3 x 1M elems
        const int wb = bid - 4096;
        const int which = wb >> 10;
        src = (which == 0) ? wq : (which == 1) ? wk : wv;
        dst = Wb + (size_t)which * HID * HID;
        off = (size_t)(wb & 1023) * 1024;
    }
    const size_t idx = off + threadIdx.x * 4;
    float4 x = *(const float4*)(src + idx);
    *(ushort4*)(dst + idx) = make_ushort4(f2bf(x.x), f2bf(x.y), f2bf(x.z), f2bf(x.w));
}

// ---------------------------------------------------------------------------
// QKV projection: 128x128 tile, BK=64, XOR-swizzled LDS via pre-swizzled
// global_load_lds source.  Q,K -> [n][s][d] bf16;  V -> V^T [n][d][s] bf16.
// (unchanged this round)
// ---------------------------------------------------------------------------
__global__ __launch_bounds__(256, 3) void qkv_mfma(
    const u16* __restrict__ Xb, const u16* __restrict__ Wb,
    const float* __restrict__ bq, const float* __restrict__ bk,
    const float* __restrict__ bv,
    u16* __restrict__ Qb, u16* __restrict__ Kb, u16* __restrict__ VT)
{
    const int m0 = blockIdx.x * 128;
    const int n0 = blockIdx.y * 128;
    const int which = blockIdx.z;

    __shared__ __align__(16) u16 As[128 * 64];   // 16 KB
    __shared__ __align__(16) u16 Bs[128 * 64];   // 16 KB

    const int tid = threadIdx.x;
    const int lane = tid & 63;
    const int w = tid >> 6;
    const int wm = w & 1, wn = w >> 1;
    const int quad = lane >> 4;
    const int l15 = lane & 15;
    const int r7 = l15 & 7;

    const u16* W = Wb + (size_t)which * HID * HID;

    f32x4 acc[4][4];
    #pragma unroll
    for (int i = 0; i < 4; ++i)
        #pragma unroll
        for (int j = 0; j < 4; ++j)
            #pragma unroll
            for (int r = 0; r < 4; ++r) acc[i][j][r] = 0.0f;

    const int srow = lane >> 3;
    const int scg  = ((lane & 7) ^ srow) * 8;    // u16 units

    for (int k0 = 0; k0 < HID; k0 += 64) {
        #pragma unroll
        for (int c = 0; c < 4; ++c) {
            const int seg = w * 4 + c;
            const int row = seg * 8 + srow;
            gll16(Xb + (size_t)(m0 + row) * HID + k0 + scg, As + seg * 512);
            gll16(W  + (size_t)(n0 + row) * HID + k0 + scg, Bs + seg * 512);
        }
        __syncthreads();

        #pragma unroll
        for (int kk = 0; kk < 2; ++kk) {
            const int xo = ((kk * 4 + quad) ^ r7) * 8;   // swizzled 16B slot
            bf16x8 af[4], bf[4];
            #pragma unroll
            for (int i = 0; i < 4; ++i)
                af[i] = *(const bf16x8*)(As + (wm * 64 + i * 16 + l15) * 64 + xo);
            #pragma unroll
            for (int j = 0; j < 4; ++j)
                bf[j] = *(const bf16x8*)(Bs + (wn * 64 + j * 16 + l15) * 64 + xo);
            #pragma unroll
            for (int i = 0; i < 4; ++i)
                #pragma unroll
                for (int j = 0; j < 4; ++j)
                    acc[i][j] = __builtin_amdgcn_mfma_f32_16x16x32_bf16(
                        af[i], bf[j], acc[i][j], 0, 0, 0);
        }
        __syncthreads();
    }

    const float* bias = (which == 0) ? bq : (which == 1) ? bk : bv;
    #pragma unroll
    for (int j = 0; j < 4; ++j) {
        const int o = n0 + wn * 64 + j * 16 + l15;
        const float bias_v = bias[o];
        const int head = o >> 6, d = o & 63;
        #pragma unroll
        for (int i = 0; i < 4; ++i) {
            const int mbase = m0 + wm * 64 + i * 16 + quad * 4;
            const int s = mbase >> 2;
            #pragma unroll
            for (int r = 0; r < 4; ++r) {
                const int n = r * NHEADS + head;
                const u16 hv = f2bf(acc[i][j][r] + bias_v);
                if (which == 0)
                    Qb[((size_t)n * S_LEN + s) * DHEAD + d] = hv;
                else if (which == 1)
                    Kb[((size_t)n * S_LEN + s) * DHEAD + d] = hv;
                else
                    VT[(size_t)n * (DHEAD * S_LEN) + (size_t)d * S_LEN + s] = hv;
            }
        }
    }
}

// ---------------------------------------------------------------------------
// Flash attention, transposed-score, P kept IN REGISTERS (no Ps LDS).
// QBLK=128: 512 blocks = exactly 2/CU, no tail round; 4 waves x 32 q.
// Per 64-key tile:
//   P^T = K·Q^T (swapped operands): lane(quad,l15) holds P pairs
//       t'e = 16j + 4*quad + 2pr  for its q = w*32+mi*16+l15.
//   8x v_cvt_pk_bf16_f32 + 4x v_permlane16_swap_b32 (lane<->lane+16,
//   q-preserving) regroup to two 8-wide t-chunks per quad:
//       quad0:{0,4} quad1:{2,6} quad2:{1,5} quad3:{3,7}
//   The chunk<->quad mismatch is absorbed into the V-read offsets:
//   PV k-chunk(st,quad) consumes t-chunk st*4 + perm[quad], perm=[0,2,1,3]
//   (k-axis permutation, legal since P and V agree).
//   O^T += V^T·P^T with pf straight from registers.
// Mask row pre-transformed to exp2 domain in LDS (broadcast reads).
// smem 36864 B; XCD-chunked swizzle (8 whole heads per XCD).
// ---------------------------------------------------------------------------
__global__ __launch_bounds__(256, 2) void attn_mfma(
    const u16* __restrict__ Qb, const u16* __restrict__ Kb,
    const u16* __restrict__ VT, const float* __restrict__ mask,
    float* __restrict__ out)
{
    const int bid = blockIdx.x;
    const int swz = (bid & 7) * 64 + (bid >> 3);   // bijective, 512%8==0
    const int n = swz >> 3;
    const int s0 = (swz & 7) * 128;
    const int b = n >> 4, head = n & 15;

    __shared__ __align__(16) char smem[36864];
    u16* Kbuf = (u16*)smem;             // [2][4096] u16 = 16 KB
    u16* Vbuf = (u16*)(smem + 16384);   // [2][4096] u16 = 16 KB
    float* Ms = (float*)(smem + 32768); // [1024] f32 = 4 KB (exp2-domain mask)
    float* Of = (float*)smem;           // [128][72] f32 overlay, epilogue

    const int tid = threadIdx.x;
    const int lane = tid & 63;
    const int w = tid >> 6;
    const int quad = lane >> 4;
    const int l15 = lane & 15;
    const int r7 = l15 & 7;
    const size_t nbase = (size_t)n * S_LEN * DHEAD;

    const float LOG2E = 1.44269504f;
    const float SCL2  = 0.18033688f;    // 0.125 * log2(e)
    const float MOFF  = -23.0831099f;   // -16 * log2(e)

    // K-read chunk offsets (chunk = st*4+quad, XOR bank swizzle)
    const int xs0 = ((quad ^ r7) * 8);
    const int xs1 = (((4 + quad) ^ r7) * 8);
    // V-read chunk offsets: chunk = st*4 + perm[quad], perm = [0,2,1,3]
    const int qperm = ((quad & 1) << 1) | (quad >> 1);
    const int xv0 = ((qperm ^ r7) * 8);
    const int xv1 = (((4 + qperm) ^ r7) * 8);

    // staging lane mapping (XOR-permuted global chunk -> swizzled LDS tile)
    const int srow = lane >> 3;
    const int scg  = (lane & 7) ^ (srow & 7);

    // mask row -> LDS, pre-transformed (before first barrier)
    {
        float4 mv = *(const float4*)(mask + (size_t)n * S_LEN + tid * 4);
        Ms[tid * 4 + 0] = fmaf(mv.x, LOG2E, MOFF);
        Ms[tid * 4 + 1] = fmaf(mv.y, LOG2E, MOFF);
        Ms[tid * 4 + 2] = fmaf(mv.z, LOG2E, MOFF);
        Ms[tid * 4 + 3] = fmaf(mv.w, LOG2E, MOFF);
    }

    // Q fragments in registers (MFMA B-operand: Q^T); wave owns 32 q
    bf16x8 qf[2][2];
    #pragma unroll
    for (int mi = 0; mi < 2; ++mi)
        #pragma unroll
        for (int st = 0; st < 2; ++st)
            qf[mi][st] = *(const bf16x8*)(Qb + nbase +
                (size_t)(s0 + w * 32 + mi * 16 + l15) * 64 + st * 32 + quad * 8);

    f32x4 O[2][4];          // O^T[d][q] accumulators
    float l_lane[2];
    #pragma unroll
    for (int mi = 0; mi < 2; ++mi) {
        l_lane[mi] = 0.0f;
        #pragma unroll
        for (int jt = 0; jt < 4; ++jt)
            #pragma unroll
            for (int r = 0; r < 4; ++r) O[mi][jt][r] = 0.0f;
    }

    // prefetch tile 0
    {
        #pragma unroll
        for (int c = 0; c < 2; ++c) {
            const int seg = w * 2 + c;
            const int row = seg * 8 + srow;
            gll16(Kb + nbase + (size_t)row * 64 + scg * 8, Kbuf + seg * 512);
            gll16(VT + nbase + (size_t)row * S_LEN + scg * 8, Vbuf + seg * 512);
        }
    }
    __syncthreads();

    for (int it = 0; it < 16; ++it) {
        const int t0 = it * 64;
        const u16* kb = Kbuf + (it & 1) * 4096;
        const u16* vb = Vbuf + (it & 1) * 4096;

        if (it < 15) {
            u16* kd = Kbuf + ((it + 1) & 1) * 4096;
            u16* vd = Vbuf + ((it + 1) & 1) * 4096;
            #pragma unroll
            for (int c = 0; c < 2; ++c) {
                const int seg = w * 2 + c;
                const int row = seg * 8 + srow;
                gll16(Kb + nbase + (size_t)(t0 + 64 + row) * 64 + scg * 8, kd + seg * 512);
                gll16(VT + nbase + (size_t)row * S_LEN + t0 + 64 + scg * 8, vd + seg * 512);
            }
        }

        // ---- P^T = K·Q^T : sc[mi][j] rows t'=quad*4+r, col q=l15 ----
        f32x4 sc[2][4];
        #pragma unroll
        for (int mi = 0; mi < 2; ++mi)
            #pragma unroll
            for (int j = 0; j < 4; ++j)
                #pragma unroll
                for (int r = 0; r < 4; ++r) sc[mi][j][r] = 0.0f;

        __builtin_amdgcn_s_setprio(1);
        #pragma unroll
        for (int st = 0; st < 2; ++st) {
            const int xo = st ? xs1 : xs0;
            bf16x8 kf[4];
            #pragma unroll
            for (int j = 0; j < 4; ++j)
                kf[j] = *(const bf16x8*)(kb + (j * 16 + l15) * 64 + xo);
            #pragma unroll
            for (int mi = 0; mi < 2; ++mi)
                #pragma unroll
                for (int j = 0; j < 4; ++j)
                    sc[mi][j] = __builtin_amdgcn_mfma_f32_16x16x32_bf16(
                        kf[j], qf[mi][st], sc[mi][j], 0, 0, 0);
        }
        __builtin_amdgcn_s_setprio(0);

        // ---- softmax (fixed max, exp2) -> bf16 pack -> lane regroup ----
        float4 mb4[4];
        #pragma unroll
        for (int j = 0; j < 4; ++j)
            mb4[j] = *(const float4*)(Ms + t0 + j * 16 + quad * 4);

        u32 pw[2][2][4];   // [mi][st][word], all indices compile-time
        #pragma unroll
        for (int mi = 0; mi < 2; ++mi) {
            float pj[4][4];
            #pragma unroll
            for (int j = 0; j < 4; ++j) {
                pj[j][0] = fexp2(fmaf(sc[mi][j][0], SCL2, mb4[j].x));
                pj[j][1] = fexp2(fmaf(sc[mi][j][1], SCL2, mb4[j].y));
                pj[j][2] = fexp2(fmaf(sc[mi][j][2], SCL2, mb4[j].z));
                pj[j][3] = fexp2(fmaf(sc[mi][j][3], SCL2, mb4[j].w));
                l_lane[mi] += (pj[j][0] + pj[j][1]) + (pj[j][2] + pj[j][3]);
            }
            u32 W00 = cvtpk(pj[0][0], pj[0][1]), W01 = cvtpk(pj[0][2], pj[0][3]);
            u32 W10 = cvtpk(pj[1][0], pj[1][1]), W11 = cvtpk(pj[1][2], pj[1][3]);
            u32 W20 = cvtpk(pj[2][0], pj[2][1]), W21 = cvtpk(pj[2][2], pj[2][3]);
            u32 W30 = cvtpk(pj[3][0], pj[3][1]), W31 = cvtpk(pj[3][2], pj[3][3]);
            pl16swap(W00, W10); pl16swap(W01, W11);
            pl16swap(W20, W30); pl16swap(W21, W31);
            pw[mi][0][0] = W00; pw[mi][0][1] = W01;
            pw[mi][0][2] = W10; pw[mi][0][3] = W11;
            pw[mi][1][0] = W20; pw[mi][1][1] = W21;
            pw[mi][1][2] = W30; pw[mi][1][3] = W31;
        }

        // ---- O^T += V^T·P^T (pf from registers; V chunks permuted) ----
        __builtin_amdgcn_s_setprio(1);
        #pragma unroll
        for (int st = 0; st < 2; ++st) {
            const int xo = st ? xv1 : xv0;
            bf16x8 vf[4];
            #pragma unroll
            for (int jt = 0; jt < 4; ++jt)
                vf[jt] = *(const bf16x8*)(vb + (jt * 16 + l15) * 64 + xo);
            #pragma unroll
            for (int mi = 0; mi < 2; ++mi) {
                union { u32 wds[4]; bf16x8 v; } pu;
                pu.wds[0] = pw[mi][st][0]; pu.wds[1] = pw[mi][st][1];
                pu.wds[2] = pw[mi][st][2]; pu.wds[3] = pw[mi][st][3];
                #pragma unroll
                for (int jt = 0; jt < 4; ++jt)
                    O[mi][jt] = __builtin_amdgcn_mfma_f32_16x16x32_bf16(
                        vf[jt], pu.v, O[mi][jt], 0, 0, 0);
            }
        }
        __builtin_amdgcn_s_setprio(0);

        __syncthreads();   // buffer reads done; next prefetch may overwrite
    }

    // ---- epilogue ----
    float inv_l[2];
    #pragma unroll
    for (int mi = 0; mi < 2; ++mi) {
        float l = l_lane[mi];
        l += __shfl_xor(l, 16);
        l += __shfl_xor(l, 32);
        inv_l[mi] = 1.0f / l;
    }
    __syncthreads();   // all waves done with Kbuf/Vbuf before overlay

    #pragma unroll
    for (int mi = 0; mi < 2; ++mi) {
        const int q = w * 32 + mi * 16 + l15;
        #pragma unroll
        for (int jt = 0; jt < 4; ++jt)
            #pragma unroll
            for (int r = 0; r < 4; ++r)
                Of[q * 72 + jt * 16 + quad * 4 + r] = O[mi][jt][r] * inv_l[mi];
    }
    __syncthreads();

    const int tx = tid & 15, ty = tid >> 4;
    #pragma unroll
    for (int p = 0; p < 8; ++p) {
        const int q = p * 16 + ty;
        float4 v = *(const float4*)(Of + q * 72 + tx * 4);
        *(float4*)(out + (size_t)(s0 + q) * (BATCH * HID) + (size_t)b * HID +
                   head * DHEAD + tx * 4) = v;
    }
}

extern "C" void kernel_launch(void* const* d_in, const int* in_sizes, int n_in,
                              void* d_out, int out_size, void* d_ws, size_t ws_size,
                              hipStream_t stream)
{
    const float* X    = (const float*)d_in[0];
    const float* mask = (const float*)d_in[1];
    const float* Wq   = (const float*)d_in[2];
    const float* bq   = (const float*)d_in[3];
    const float* Wk   = (const float*)d_in[4];
    const float* bk   = (const float*)d_in[5];
    const float* Wv   = (const float*)d_in[6];
    const float* bv   = (const float*)d_in[7];
    float* out = (float*)d_out;

    const size_t MX = (size_t)M_ROWS * HID;   // 4M elems
    const size_t MW = (size_t)HID * HID;      // 1M elems
    u16* wsp = (u16*)d_ws;
    u16* Xb = wsp;
    u16* Wb = Xb + MX;          // 3 matrices
    u16* Qb = Wb + 3 * MW;
    u16* Kb = Qb + MX;
    u16* VT = Kb + MX;          // total 19M u16 = 38 MB

    cvt_all<<<dim3(4096 + 3072), 256, 0, stream>>>(X, Wq, Wk, Wv, Xb, Wb);
    qkv_mfma<<<dim3(M_ROWS / 128, HID / 128, 3), 256, 0, stream>>>(
        Xb, Wb, bq, bk, bv, Qb, Kb, VT);
    attn_mfma<<<dim3(S_LEN / 128 * NTOT), 256, 0, stream>>>(Qb, Kb, VT, mask, out);
}

// Round 4
// 143.919 us; speedup vs baseline: 1.0892x; 1.0180x over previous
//
#include <hip/hip_runtime.h>
#include <hip/hip_bf16.h>
#include <math.h>

#define S_LEN 1024
#define BATCH 4
#define HID 1024
#define NHEADS 16
#define DHEAD 64
#define NTOT 64
#define M_ROWS 4096

typedef unsigned short u16;
typedef unsigned int u32;
typedef __bf16 bf16x8 __attribute__((ext_vector_type(8)));
typedef float f32x4 __attribute__((ext_vector_type(4)));

__device__ __forceinline__ u16 f2bf(float x) {
    __hip_bfloat16 h = __float2bfloat16(x);
    return *(u16*)&h;
}

__device__ __forceinline__ float fexp2(float x) {
#if __has_builtin(__builtin_amdgcn_exp2f)
    return __builtin_amdgcn_exp2f(x);
#else
    return __expf(x * 0.6931471805599453f);
#endif
}

// pack two f32 -> one u32 of 2x bf16 (RNE), gfx950 v_cvt_pk_bf16_f32
__device__ __forceinline__ u32 cvtpk(float a, float b) {
    u32 r;
    asm("v_cvt_pk_bf16_f32 %0, %1, %2" : "=v"(r) : "v"(a), "v"(b));
    return r;
}

// swap lanes 16-31 of a with lanes 0-15 of b (and 48-63 with 32-47)
__device__ __forceinline__ void pl16swap(u32& a, u32& b) {
    asm("v_permlane16_swap_b32 %0, %1" : "+v"(a), "+v"(b));
}

// async global->LDS, 16B/lane; LDS dest = wave-uniform base + lane*16
__device__ __forceinline__ void gll16(const u16* g, u16* l) {
    __builtin_amdgcn_global_load_lds(
        (const __attribute__((address_space(1))) u32*)g,
        (__attribute__((address_space(3))) u32*)l, 16, 0, 0);
}

// ---------------------------------------------------------------------------
// fused fp32 -> bf16 convert for X and the three W matrices
// ---------------------------------------------------------------------------
__global__ __launch_bounds__(256) void cvt_all(
    const float* __restrict__ X, const float* __restrict__ wq,
    const float* __restrict__ wk, const float* __restrict__ wv,
    u16* __restrict__ Xb, u16* __restrict__ Wb)
{
    const int bid = blockIdx.x;
    const float* src;
    u16* dst;
    size_t off;
    if (bid < 4096) {            // X: 4M elems
        src = X; dst = Xb; off = (size_t)bid * 1024;
    } else {                     // W: 3 x 1M elems
        const int wb = bid - 4096;
        const int which = wb >> 10;
        src = (which == 0) ? wq : (which == 1) ? wk : wv;
        dst = Wb + (size_t)which * HID * HID;
        off = (size_t)(wb & 1023) * 1024;
    }
    const size_t idx = off + threadIdx.x * 4;
    float4 x = *(const float4*)(src + idx);
    *(ushort4*)(dst + idx) = make_ushort4(f2bf(x.x), f2bf(x.y), f2bf(x.z), f2bf(x.w));
}

// ---------------------------------------------------------------------------
// QKV projection: 128x128 tile, BK=64, XOR-swizzled LDS via pre-swizzled
// global_load_lds source.  Q,K -> [n][s][d] bf16;  V -> V^T [n][d][s] bf16.
// (unchanged this round)
// ---------------------------------------------------------------------------
__global__ __launch_bounds__(256, 3) void qkv_mfma(
    const u16* __restrict__ Xb, const u16* __restrict__ Wb,
    const float* __restrict__ bq, const float* __restrict__ bk,
    const float* __restrict__ bv,
    u16* __restrict__ Qb, u16* __restrict__ Kb, u16* __restrict__ VT)
{
    const int m0 = blockIdx.x * 128;
    const int n0 = blockIdx.y * 128;
    const int which = blockIdx.z;

    __shared__ __align__(16) u16 As[128 * 64];   // 16 KB
    __shared__ __align__(16) u16 Bs[128 * 64];   // 16 KB

    const int tid = threadIdx.x;
    const int lane = tid & 63;
    const int w = tid >> 6;
    const int wm = w & 1, wn = w >> 1;
    const int quad = lane >> 4;
    const int l15 = lane & 15;
    const int r7 = l15 & 7;

    const u16* W = Wb + (size_t)which * HID * HID;

    f32x4 acc[4][4];
    #pragma unroll
    for (int i = 0; i < 4; ++i)
        #pragma unroll
        for (int j = 0; j < 4; ++j)
            #pragma unroll
            for (int r = 0; r < 4; ++r) acc[i][j][r] = 0.0f;

    const int srow = lane >> 3;
    const int scg  = ((lane & 7) ^ srow) * 8;    // u16 units

    for (int k0 = 0; k0 < HID; k0 += 64) {
        #pragma unroll
        for (int c = 0; c < 4; ++c) {
            const int seg = w * 4 + c;
            const int row = seg * 8 + srow;
            gll16(Xb + (size_t)(m0 + row) * HID + k0 + scg, As + seg * 512);
            gll16(W  + (size_t)(n0 + row) * HID + k0 + scg, Bs + seg * 512);
        }
        __syncthreads();

        #pragma unroll
        for (int kk = 0; kk < 2; ++kk) {
            const int xo = ((kk * 4 + quad) ^ r7) * 8;   // swizzled 16B slot
            bf16x8 af[4], bf[4];
            #pragma unroll
            for (int i = 0; i < 4; ++i)
                af[i] = *(const bf16x8*)(As + (wm * 64 + i * 16 + l15) * 64 + xo);
            #pragma unroll
            for (int j = 0; j < 4; ++j)
                bf[j] = *(const bf16x8*)(Bs + (wn * 64 + j * 16 + l15) * 64 + xo);
            #pragma unroll
            for (int i = 0; i < 4; ++i)
                #pragma unroll
                for (int j = 0; j < 4; ++j)
                    acc[i][j] = __builtin_amdgcn_mfma_f32_16x16x32_bf16(
                        af[i], bf[j], acc[i][j], 0, 0, 0);
        }
        __syncthreads();
    }

    const float* bias = (which == 0) ? bq : (which == 1) ? bk : bv;
    #pragma unroll
    for (int j = 0; j < 4; ++j) {
        const int o = n0 + wn * 64 + j * 16 + l15;
        const float bias_v = bias[o];
        const int head = o >> 6, d = o & 63;
        #pragma unroll
        for (int i = 0; i < 4; ++i) {
            const int mbase = m0 + wm * 64 + i * 16 + quad * 4;
            const int s = mbase >> 2;
            #pragma unroll
            for (int r = 0; r < 4; ++r) {
                const int n = r * NHEADS + head;
                const u16 hv = f2bf(acc[i][j][r] + bias_v);
                if (which == 0)
                    Qb[((size_t)n * S_LEN + s) * DHEAD + d] = hv;
                else if (which == 1)
                    Kb[((size_t)n * S_LEN + s) * DHEAD + d] = hv;
                else
                    VT[(size_t)n * (DHEAD * S_LEN) + (size_t)d * S_LEN + s] = hv;
            }
        }
    }
}

// ---------------------------------------------------------------------------
// Flash attention, transposed-score, P in registers.  KVBLK=128 this round:
// each iteration processes TWO 64-key half-tiles (h=0,1) that reuse the
// verified 64-key index math verbatim.  8 iterations (was 16) -> half the
// __syncthreads full-drains; QK(h1) MFMA can overlap softmax(h0) VALU.
// QBLK=128: 512 blocks = exactly 2/CU; 4 waves x 32 q.
//   P^T = K·Q^T (swapped operands); 8x cvt_pk + 4x permlane16_swap per
//   (mi,h) regroup P to bf16 MFMA A-fragments; chunk<->quad mismatch is
//   absorbed into V-read offsets (perm=[0,2,1,3], k-axis permutation).
// Mask row pre-transformed to exp2 domain in LDS (broadcast reads).
// LDS 68 KB (2 blocks/CU); XCD-chunked swizzle (8 whole heads per XCD).
// ---------------------------------------------------------------------------
__global__ __launch_bounds__(256, 2) void attn_mfma(
    const u16* __restrict__ Qb, const u16* __restrict__ Kb,
    const u16* __restrict__ VT, const float* __restrict__ mask,
    float* __restrict__ out)
{
    const int bid = blockIdx.x;
    const int swz = (bid & 7) * 64 + (bid >> 3);   // bijective, 512%8==0
    const int n = swz >> 3;
    const int s0 = (swz & 7) * 128;
    const int b = n >> 4, head = n & 15;

    __shared__ __align__(16) char smem[69632];
    u16* Kbuf = (u16*)smem;             // [2 dbuf][2 half][64*64] u16 = 32 KB
    u16* Vbuf = (u16*)(smem + 32768);   // [2 dbuf][2 half][64*64] u16 = 32 KB
    float* Ms = (float*)(smem + 65536); // [1024] f32 = 4 KB (exp2-domain mask)
    float* Of = (float*)smem;           // [128][72] f32 overlay, epilogue

    const int tid = threadIdx.x;
    const int lane = tid & 63;
    const int w = tid >> 6;
    const int quad = lane >> 4;
    const int l15 = lane & 15;
    const int r7 = l15 & 7;
    const size_t nbase = (size_t)n * S_LEN * DHEAD;

    const float LOG2E = 1.44269504f;
    const float SCL2  = 0.18033688f;    // 0.125 * log2(e)
    const float MOFF  = -23.0831099f;   // -16 * log2(e)

    // K-read chunk offsets (chunk = st*4+quad, XOR bank swizzle)
    const int xs0 = ((quad ^ r7) * 8);
    const int xs1 = (((4 + quad) ^ r7) * 8);
    // V-read chunk offsets: chunk = st*4 + perm[quad], perm = [0,2,1,3]
    const int qperm = ((quad & 1) << 1) | (quad >> 1);
    const int xv0 = ((qperm ^ r7) * 8);
    const int xv1 = (((4 + qperm) ^ r7) * 8);

    // staging lane mapping (XOR-permuted global chunk -> swizzled LDS tile)
    const int srow = lane >> 3;
    const int scg  = (lane & 7) ^ (srow & 7);

    // mask row -> LDS, pre-transformed (before first barrier)
    {
        float4 mv = *(const float4*)(mask + (size_t)n * S_LEN + tid * 4);
        Ms[tid * 4 + 0] = fmaf(mv.x, LOG2E, MOFF);
        Ms[tid * 4 + 1] = fmaf(mv.y, LOG2E, MOFF);
        Ms[tid * 4 + 2] = fmaf(mv.z, LOG2E, MOFF);
        Ms[tid * 4 + 3] = fmaf(mv.w, LOG2E, MOFF);
    }

    // Q fragments in registers (MFMA B-operand: Q^T); wave owns 32 q
    bf16x8 qf[2][2];
    #pragma unroll
    for (int mi = 0; mi < 2; ++mi)
        #pragma unroll
        for (int st = 0; st < 2; ++st)
            qf[mi][st] = *(const bf16x8*)(Qb + nbase +
                (size_t)(s0 + w * 32 + mi * 16 + l15) * 64 + st * 32 + quad * 8);

    f32x4 O[2][4];          // O^T[d][q] accumulators
    float l_lane[2];
    #pragma unroll
    for (int mi = 0; mi < 2; ++mi) {
        l_lane[mi] = 0.0f;
        #pragma unroll
        for (int jt = 0; jt < 4; ++jt)
            #pragma unroll
            for (int r = 0; r < 4; ++r) O[mi][jt][r] = 0.0f;
    }

    // prefetch tile 0 (both halves) into dbuf 0
    {
        #pragma unroll
        for (int h = 0; h < 2; ++h) {
            #pragma unroll
            for (int c = 0; c < 2; ++c) {
                const int seg = w * 2 + c;
                const int row = seg * 8 + srow;
                gll16(Kb + nbase + (size_t)(h * 64 + row) * 64 + scg * 8,
                      Kbuf + h * 4096 + seg * 512);
                gll16(VT + nbase + (size_t)row * S_LEN + h * 64 + scg * 8,
                      Vbuf + h * 4096 + seg * 512);
            }
        }
    }
    __syncthreads();

    u32 pw[2][2][2][4];   // [mi][h][st][word], all compile-time indexed

    for (int it = 0; it < 8; ++it) {
        const int t0 = it * 128;
        const u16* kb = Kbuf + (it & 1) * 8192;
        const u16* vb = Vbuf + (it & 1) * 8192;

        if (it < 7) {
            u16* kd = Kbuf + ((it + 1) & 1) * 8192;
            u16* vd = Vbuf + ((it + 1) & 1) * 8192;
            const int t0n = t0 + 128;
            #pragma unroll
            for (int h = 0; h < 2; ++h) {
                #pragma unroll
                for (int c = 0; c < 2; ++c) {
                    const int seg = w * 2 + c;
                    const int row = seg * 8 + srow;
                    gll16(Kb + nbase + (size_t)(t0n + h * 64 + row) * 64 + scg * 8,
                          kd + h * 4096 + seg * 512);
                    gll16(VT + nbase + (size_t)row * S_LEN + t0n + h * 64 + scg * 8,
                          vd + h * 4096 + seg * 512);
                }
            }
        }

        // ---- per half: P^T = K·Q^T, then softmax+pack (short sc lifetime)
        #pragma unroll
        for (int h = 0; h < 2; ++h) {
            const u16* kbh = kb + h * 4096;

            f32x4 sc[2][4];
            #pragma unroll
            for (int mi = 0; mi < 2; ++mi)
                #pragma unroll
                for (int j = 0; j < 4; ++j)
                    #pragma unroll
                    for (int r = 0; r < 4; ++r) sc[mi][j][r] = 0.0f;

            __builtin_amdgcn_s_setprio(1);
            #pragma unroll
            for (int st = 0; st < 2; ++st) {
                const int xo = st ? xs1 : xs0;
                bf16x8 kf[4];
                #pragma unroll
                for (int j = 0; j < 4; ++j)
                    kf[j] = *(const bf16x8*)(kbh + (j * 16 + l15) * 64 + xo);
                #pragma unroll
                for (int mi = 0; mi < 2; ++mi)
                    #pragma unroll
                    for (int j = 0; j < 4; ++j)
                        sc[mi][j] = __builtin_amdgcn_mfma_f32_16x16x32_bf16(
                            kf[j], qf[mi][st], sc[mi][j], 0, 0, 0);
            }
            __builtin_amdgcn_s_setprio(0);

            float4 mb4[4];
            #pragma unroll
            for (int j = 0; j < 4; ++j)
                mb4[j] = *(const float4*)(Ms + t0 + h * 64 + j * 16 + quad * 4);

            #pragma unroll
            for (int mi = 0; mi < 2; ++mi) {
                float pj[4][4];
                #pragma unroll
                for (int j = 0; j < 4; ++j) {
                    pj[j][0] = fexp2(fmaf(sc[mi][j][0], SCL2, mb4[j].x));
                    pj[j][1] = fexp2(fmaf(sc[mi][j][1], SCL2, mb4[j].y));
                    pj[j][2] = fexp2(fmaf(sc[mi][j][2], SCL2, mb4[j].z));
                    pj[j][3] = fexp2(fmaf(sc[mi][j][3], SCL2, mb4[j].w));
                    l_lane[mi] += (pj[j][0] + pj[j][1]) + (pj[j][2] + pj[j][3]);
                }
                u32 W00 = cvtpk(pj[0][0], pj[0][1]), W01 = cvtpk(pj[0][2], pj[0][3]);
                u32 W10 = cvtpk(pj[1][0], pj[1][1]), W11 = cvtpk(pj[1][2], pj[1][3]);
                u32 W20 = cvtpk(pj[2][0], pj[2][1]), W21 = cvtpk(pj[2][2], pj[2][3]);
                u32 W30 = cvtpk(pj[3][0], pj[3][1]), W31 = cvtpk(pj[3][2], pj[3][3]);
                pl16swap(W00, W10); pl16swap(W01, W11);
                pl16swap(W20, W30); pl16swap(W21, W31);
                pw[mi][h][0][0] = W00; pw[mi][h][0][1] = W01;
                pw[mi][h][0][2] = W10; pw[mi][h][0][3] = W11;
                pw[mi][h][1][0] = W20; pw[mi][h][1][1] = W21;
                pw[mi][h][1][2] = W30; pw[mi][h][1][3] = W31;
            }
        }

        // ---- O^T += V^T·P^T over both halves (pf from registers) ----
        __builtin_amdgcn_s_setprio(1);
        #pragma unroll
        for (int h = 0; h < 2; ++h) {
            const u16* vbh = vb + h * 4096;
            #pragma unroll
            for (int st = 0; st < 2; ++st) {
                const int xo = st ? xv1 : xv0;
                bf16x8 vf[4];
                #pragma unroll
                for (int jt = 0; jt < 4; ++jt)
                    vf[jt] = *(const bf16x8*)(vbh + (jt * 16 + l15) * 64 + xo);
                #pragma unroll
                for (int mi = 0; mi < 2; ++mi) {
                    union { u32 wds[4]; bf16x8 v; } pu;
                    pu.wds[0] = pw[mi][h][st][0]; pu.wds[1] = pw[mi][h][st][1];
                    pu.wds[2] = pw[mi][h][st][2]; pu.wds[3] = pw[mi][h][st][3];
                    #pragma unroll
                    for (int jt = 0; jt < 4; ++jt)
                        O[mi][jt] = __builtin_amdgcn_mfma_f32_16x16x32_bf16(
                            vf[jt], pu.v, O[mi][jt], 0, 0, 0);
                }
            }
        }
        __builtin_amdgcn_s_setprio(0);

        __syncthreads();   // buffer reads done; next prefetch may overwrite
    }

    // ---- epilogue ----
    float inv_l[2];
    #pragma unroll
    for (int mi = 0; mi < 2; ++mi) {
        float l = l_lane[mi];
        l += __shfl_xor(l, 16);
        l += __shfl_xor(l, 32);
        inv_l[mi] = 1.0f / l;
    }
    __syncthreads();   // all waves done with Kbuf/Vbuf before overlay

    #pragma unroll
    for (int mi = 0; mi < 2; ++mi) {
        const int q = w * 32 + mi * 16 + l15;
        #pragma unroll
        for (int jt = 0; jt < 4; ++jt)
            #pragma unroll
            for (int r = 0; r < 4; ++r)
                Of[q * 72 + jt * 16 + quad * 4 + r] = O[mi][jt][r] * inv_l[mi];
    }
    __syncthreads();

    const int tx = tid & 15, ty = tid >> 4;
    #pragma unroll
    for (int p = 0; p < 8; ++p) {
        const int q = p * 16 + ty;
        float4 v = *(const float4*)(Of + q * 72 + tx * 4);
        *(float4*)(out + (size_t)(s0 + q) * (BATCH * HID) + (size_t)b * HID +
                   head * DHEAD + tx * 4) = v;
    }
}

extern "C" void kernel_launch(void* const* d_in, const int* in_sizes, int n_in,
                              void* d_out, int out_size, void* d_ws, size_t ws_size,
                              hipStream_t stream)
{
    const float* X    = (const float*)d_in[0];
    const float* mask = (const float*)d_in[1];
    const float* Wq   = (const float*)d_in[2];
    const float* bq   = (const float*)d_in[3];
    const float* Wk   = (const float*)d_in[4];
    const float* bk   = (const float*)d_in[5];
    const float* Wv   = (const float*)d_in[6];
    const float* bv   = (const float*)d_in[7];
    float* out = (float*)d_out;

    const size_t MX = (size_t)M_ROWS * HID;   // 4M elems
    const size_t MW = (size_t)HID * HID;      // 1M elems
    u16* wsp = (u16*)d_ws;
    u16* Xb = wsp;
    u16* Wb = Xb + MX;          // 3 matrices
    u16* Qb = Wb + 3 * MW;
    u16* Kb = Qb + MX;
    u16* VT = Kb + MX;          // total 19M u16 = 38 MB

    cvt_all<<<dim3(4096 + 3072), 256, 0, stream>>>(X, Wq, Wk, Wv, Xb, Wb);
    qkv_mfma<<<dim3(M_ROWS / 128, HID / 128, 3), 256, 0, stream>>>(
        Xb, Wb, bq, bk, bv, Qb, Kb, VT);
    attn_mfma<<<dim3(S_LEN / 128 * NTOT), 256, 0, stream>>>(Qb, Kb, VT, mask, out);
}